// Round 2
// baseline (388.463 us; speedup 1.0000x reference)
//
#include <hip/hip_runtime.h>
#include <math.h>

#define B_ 16
#define N_ 8400
#define M_ 32
#define C_ 80
#define TOPK_ 13
#define NB_ ((N_ + 255) / 256)

// ---------------------------------------------------------------------------
// Decode mask_gt robustly: it may arrive as 1-byte bool or int32.
// True mask is a per-row prefix (1s then 0s) with >=1 one (counts in 1..M).
// int32-as-bytes misread provably violates that pattern, so validate & fall back.
__global__ void k_decode_mask(const unsigned char* __restrict__ raw,
                              unsigned char* __restrict__ mask) {
    if (blockIdx.x != 0 || threadIdx.x != 0) return;
    bool ok = true;
    for (int b = 0; b < B_ && ok; ++b) {
        int cnt = 0; bool seen_zero = false;
        for (int m = 0; m < M_; ++m) {
            unsigned char v = raw[b * M_ + m];
            if (v > 1) { ok = false; break; }
            if (v) { if (seen_zero) { ok = false; break; } ++cnt; }
            else seen_zero = true;
        }
        if (cnt < 1) ok = false;
    }
    if (ok) {
        for (int i = 0; i < B_ * M_; ++i) mask[i] = raw[i] ? 1 : 0;
    } else {
        const int* ri = (const int*)raw;
        for (int i = 0; i < B_ * M_; ++i) mask[i] = (ri[i] != 0) ? 1 : 0;
    }
}

// Precompute atan(w/h) per gt box (depends only on (b,m)) in fp64.
__global__ void k_pre_g(const float* __restrict__ gt_bboxes,
                        double* __restrict__ atan_g) {
    int i = blockIdx.x * blockDim.x + threadIdx.x;
    if (i >= B_ * M_) return;
    double x1 = gt_bboxes[i * 4 + 0], y1 = gt_bboxes[i * 4 + 1];
    double x2 = gt_bboxes[i * 4 + 2], y2 = gt_bboxes[i * 4 + 3];
    double w = x2 - x1, h = y2 - y1 + 1e-7;
    atan_g[i] = atan(w / h);
}

// Precompute atan(w/h) per predicted box (depends only on (b,n)) in fp64.
__global__ void k_pre_p(const float* __restrict__ pd_bboxes,
                        double* __restrict__ atan_p) {
    int i = blockIdx.x * blockDim.x + threadIdx.x;
    if (i >= B_ * N_) return;
    double x1 = pd_bboxes[(size_t)i * 4 + 0], y1 = pd_bboxes[(size_t)i * 4 + 1];
    double x2 = pd_bboxes[(size_t)i * 4 + 2], y2 = pd_bboxes[(size_t)i * 4 + 3];
    double w = x2 - x1, h = y2 - y1 + 1e-7;
    atan_p[i] = atan(w / h);
}

// ---------------------------------------------------------------------------
// K1: per (b,m,n) compute valid, overlaps (CIoU clipped), align metric (fp64).
__global__ __launch_bounds__(256) void k_metric(
    const float* __restrict__ pd_scores, const float* __restrict__ pd_bboxes,
    const float* __restrict__ anc, const int* __restrict__ gt_labels,
    const float* __restrict__ gt_bboxes, const unsigned char* __restrict__ mask,
    const double* __restrict__ atan_p, const double* __restrict__ atan_g,
    double* __restrict__ OV, double* __restrict__ AM,
    unsigned char* __restrict__ VALID) {
    int b = blockIdx.y;
    int n = blockIdx.x * 256 + threadIdx.x;

    __shared__ float s_g[M_][4];
    __shared__ int s_cls[M_];
    __shared__ unsigned char s_mask[M_];
    __shared__ double s_atg[M_];
    if (threadIdx.x < M_) {
        int gi = b * M_ + threadIdx.x;
        s_g[threadIdx.x][0] = gt_bboxes[gi * 4 + 0];
        s_g[threadIdx.x][1] = gt_bboxes[gi * 4 + 1];
        s_g[threadIdx.x][2] = gt_bboxes[gi * 4 + 2];
        s_g[threadIdx.x][3] = gt_bboxes[gi * 4 + 3];
        s_cls[threadIdx.x] = gt_labels[gi];
        s_mask[threadIdx.x] = mask[gi];
        s_atg[threadIdx.x] = atan_g[gi];
    }
    __syncthreads();
    if (n >= N_) return;

    double ax = anc[n * 2 + 0], ay = anc[n * 2 + 1];
    size_t pb = ((size_t)b * N_ + n) * 4;
    double px1 = pd_bboxes[pb + 0], py1 = pd_bboxes[pb + 1];
    double px2 = pd_bboxes[pb + 2], py2 = pd_bboxes[pb + 3];
    double atp = atan_p[(size_t)b * N_ + n];
    const float* sc = pd_scores + ((size_t)b * N_ + n) * C_;

    for (int m = 0; m < M_; ++m) {
        double gx1 = s_g[m][0], gy1 = s_g[m][1], gx2 = s_g[m][2], gy2 = s_g[m][3];
        bool inb = (ax - gx1 > 1e-9) && (ay - gy1 > 1e-9) &&
                   (gx2 - ax > 1e-9) && (gy2 - ay > 1e-9);
        bool val = inb && (s_mask[m] != 0);
        double ov = 0.0, am = 0.0;
        if (val) {
            double iw = fmin(gx2, px2) - fmax(gx1, px1); iw = iw > 0.0 ? iw : 0.0;
            double ih = fmin(gy2, py2) - fmax(gy1, py1); ih = ih > 0.0 ? ih : 0.0;
            double inter = iw * ih;
            double w1 = gx2 - gx1, h1 = gy2 - gy1 + 1e-7;
            double w2 = px2 - px1, h2 = py2 - py1 + 1e-7;
            double uni = w1 * h1 + w2 * h2 - inter + 1e-7;
            double iou = inter / uni;
            double cw = fmax(gx2, px2) - fmin(gx1, px1);
            double ch = fmax(gy2, py2) - fmin(gy1, py1);
            double c2 = cw * cw + ch * ch + 1e-7;
            double dx = px1 + px2 - gx1 - gx2, dy = py1 + py2 - gy1 - gy2;
            double rho2 = (dx * dx + dy * dy) * 0.25;
            double dv = atp - s_atg[m];
            double v = (4.0 / (M_PI * M_PI)) * dv * dv;
            double a = v / (v - iou + (1.0 + 1e-7));
            double ciou = iou - (rho2 / c2 + v * a);
            ov = ciou > 0.0 ? ciou : 0.0;
            double o2 = ov * ov;
            am = (double)sc[s_cls[m]] * (o2 * o2 * o2);
        }
        size_t idx = ((size_t)b * M_ + m) * N_ + n;
        OV[idx] = ov;
        AM[idx] = am;
        VALID[idx] = val ? 1 : 0;
    }
}

// ---------------------------------------------------------------------------
// K2: per valid (b,m) row, iterative top-13 argmax (ties -> lowest index),
// scatter mask_pos = valid at selected indices.
__global__ __launch_bounds__(256) void k_topk(
    const double* __restrict__ AM, const unsigned char* __restrict__ VALID,
    const unsigned char* __restrict__ mask, unsigned char* __restrict__ MP) {
    int row = blockIdx.x;  // b*M + m
    __shared__ double sv[256];
    __shared__ int si[256];
    __shared__ int chosen[TOPK_];
    if (!mask[row]) return;
    const double* r = AM + (size_t)row * N_;
    int t = threadIdx.x;

    for (int k = 0; k < TOPK_; ++k) {
        double bv = -1.0; int bi = N_;
        for (int i = t; i < N_; i += 256) {
            double v = r[i];
            bool skip = false;
            for (int j = 0; j < k; ++j) skip |= (chosen[j] == i);
            if (!skip && (v > bv || (v == bv && i < bi))) { bv = v; bi = i; }
        }
        sv[t] = bv; si[t] = bi;
        __syncthreads();
        for (int s = 128; s > 0; s >>= 1) {
            if (t < s) {
                if (sv[t + s] > sv[t] || (sv[t + s] == sv[t] && si[t + s] < si[t])) {
                    sv[t] = sv[t + s]; si[t] = si[t + s];
                }
            }
            __syncthreads();
        }
        if (t == 0) chosen[k] = si[0];
        __syncthreads();
    }
    if (t < TOPK_) {
        int idx = chosen[t];
        MP[(size_t)row * N_ + idx] = VALID[(size_t)row * N_ + idx];
    }
}

// ---------------------------------------------------------------------------
// K3: per (b,n) resolve assignment; atomic-max per-gt pos_align/pos_over.
__global__ __launch_bounds__(256) void k_assign(
    const double* __restrict__ OV, const unsigned char* __restrict__ MP,
    const double* __restrict__ AM, int* __restrict__ TG,
    unsigned char* __restrict__ FG, unsigned long long* __restrict__ PAL,
    unsigned long long* __restrict__ POV) {
    int b = blockIdx.y;
    int n = blockIdx.x * 256 + threadIdx.x;
    if (n >= N_) return;

    int cnt = 0, first = -1, bestm = 0;
    double bestov = -1.0;
    for (int m = 0; m < M_; ++m) {
        size_t idx = ((size_t)b * M_ + m) * N_ + n;
        double ov = OV[idx];
        if (MP[idx]) { cnt++; if (first < 0) first = m; }
        if (ov > bestov) { bestov = ov; bestm = m; }  // strict > = first max
    }
    int tg; unsigned char fg;
    if (cnt > 1)      { tg = bestm; fg = 1; }
    else if (cnt == 1){ tg = first; fg = 1; }
    else              { tg = 0;     fg = 0; }
    TG[b * N_ + n] = tg;
    FG[b * N_ + n] = fg;
    if (fg) {
        size_t idx = ((size_t)b * M_ + tg) * N_ + n;
        // values are >= 0 so bit-pattern compare == float compare
        atomicMax(&PAL[b * M_ + tg], (unsigned long long)__double_as_longlong(AM[idx]));
        atomicMax(&POV[b * M_ + tg], (unsigned long long)__double_as_longlong(OV[idx]));
    }
}

// ---------------------------------------------------------------------------
// K4: emit outputs (concatenated float32): labels, bboxes, scores(scatter),
// fg_mask, target_gt_idx. d_out pre-zeroed by memset.
__global__ __launch_bounds__(256) void k_out(
    const int* __restrict__ TG, const unsigned char* __restrict__ FG,
    const int* __restrict__ gt_labels, const float* __restrict__ gt_bboxes,
    const double* __restrict__ AM, const unsigned long long* __restrict__ PAL,
    const unsigned long long* __restrict__ POV, float* __restrict__ out) {
    int b = blockIdx.y;
    int n = blockIdx.x * 256 + threadIdx.x;
    if (n >= N_) return;
    int i = b * N_ + n;
    int tg = TG[i];
    int fg = FG[i];
    int lab = gt_labels[b * M_ + tg];

    float* o0 = out;                            // labels  (B,N)
    float* o1 = out + (size_t)B_ * N_;          // bboxes  (B,N,4)
    float* o2 = out + (size_t)B_ * N_ * 5;      // scores  (B,N,C)
    float* o3 = out + (size_t)B_ * N_ * 85;     // fg_mask (B,N)
    float* o4 = out + (size_t)B_ * N_ * 86;     // tg_idx  (B,N)

    o0[i] = (float)lab;
    const float* gb = gt_bboxes + ((size_t)b * M_ + tg) * 4;
    o1[(size_t)i * 4 + 0] = gb[0];
    o1[(size_t)i * 4 + 1] = gb[1];
    o1[(size_t)i * 4 + 2] = gb[2];
    o1[(size_t)i * 4 + 3] = gb[3];
    o3[i] = fg ? 1.0f : 0.0f;
    o4[i] = (float)tg;
    if (fg) {
        double am = AM[((size_t)b * M_ + tg) * N_ + n];
        double pal = __longlong_as_double((long long)PAL[b * M_ + tg]);
        double pov = __longlong_as_double((long long)POV[b * M_ + tg]);
        double na = am * pov / (pal + 1e-9);
        o2[(size_t)i * C_ + lab] = (float)na;
    }
}

// ---------------------------------------------------------------------------
extern "C" void kernel_launch(void* const* d_in, const int* in_sizes, int n_in,
                              void* d_out, int out_size, void* d_ws, size_t ws_size,
                              hipStream_t stream) {
    const float* pd_scores = (const float*)d_in[0];
    const float* pd_bboxes = (const float*)d_in[1];
    const float* anc       = (const float*)d_in[2];
    const int*   gt_labels = (const int*)d_in[3];
    const float* gt_bboxes = (const float*)d_in[4];
    const unsigned char* mask_raw = (const unsigned char*)d_in[5];

    char* ws = (char*)d_ws;
    size_t off = 0;
    double* OV  = (double*)(ws + off); off += (size_t)B_ * M_ * N_ * 8;
    double* AM  = (double*)(ws + off); off += (size_t)B_ * M_ * N_ * 8;
    double* ATP = (double*)(ws + off); off += (size_t)B_ * N_ * 8;
    double* ATG = (double*)(ws + off); off += (size_t)B_ * M_ * 8;
    unsigned long long* PAL = (unsigned long long*)(ws + off); off += (size_t)B_ * M_ * 8;
    unsigned long long* POV = (unsigned long long*)(ws + off); off += (size_t)B_ * M_ * 8;
    int* TG = (int*)(ws + off); off += (size_t)B_ * N_ * 4;
    unsigned char* VALID = (unsigned char*)(ws + off); off += (size_t)B_ * M_ * N_;
    unsigned char* MP    = (unsigned char*)(ws + off); off += (size_t)B_ * M_ * N_;
    unsigned char* FG    = (unsigned char*)(ws + off); off += (size_t)B_ * N_;
    unsigned char* MASK  = (unsigned char*)(ws + off); off += (size_t)B_ * M_;

    // zero-init: outputs (scores region must be 0), mask_pos, pos_align/pos_over
    hipMemsetAsync(d_out, 0, (size_t)out_size * sizeof(float), stream);
    hipMemsetAsync(MP, 0, (size_t)B_ * M_ * N_, stream);
    hipMemsetAsync(PAL, 0, (size_t)B_ * M_ * 8 * 2, stream);  // PAL+POV adjacent

    k_decode_mask<<<1, 64, 0, stream>>>(mask_raw, MASK);
    k_pre_g<<<(B_ * M_ + 255) / 256, 256, 0, stream>>>(gt_bboxes, ATG);
    k_pre_p<<<(B_ * N_ + 255) / 256, 256, 0, stream>>>(pd_bboxes, ATP);

    dim3 gbn(NB_, B_);
    k_metric<<<gbn, 256, 0, stream>>>(pd_scores, pd_bboxes, anc, gt_labels,
                                      gt_bboxes, MASK, ATP, ATG, OV, AM, VALID);
    k_topk<<<B_ * M_, 256, 0, stream>>>(AM, VALID, MASK, MP);
    k_assign<<<gbn, 256, 0, stream>>>(OV, MP, AM, TG, FG, PAL, POV);
    k_out<<<gbn, 256, 0, stream>>>(TG, FG, gt_labels, gt_bboxes, AM, PAL, POV,
                                   (float*)d_out);
}

// Round 3
// 205.913 us; speedup vs baseline: 1.8865x; 1.8865x over previous
//
#include <hip/hip_runtime.h>
#include <math.h>

#define B_ 16
#define N_ 8400
#define M_ 32
#define C_ 80
#define TOPK_ 13
#define NB_ ((N_ + 255) / 256)

// ---------------------------------------------------------------------------
// Decode mask_gt robustly: it may arrive as 1-byte bool or int32.
// True mask is a per-row prefix (1s then 0s) with >=1 one (counts in 1..M).
// int32-as-bytes misread provably violates that pattern, so validate & fall back.
__global__ void k_decode_mask(const unsigned char* __restrict__ raw,
                              unsigned char* __restrict__ mask) {
    if (blockIdx.x != 0 || threadIdx.x != 0) return;
    bool ok = true;
    for (int b = 0; b < B_ && ok; ++b) {
        int cnt = 0; bool seen_zero = false;
        for (int m = 0; m < M_; ++m) {
            unsigned char v = raw[b * M_ + m];
            if (v > 1) { ok = false; break; }
            if (v) { if (seen_zero) { ok = false; break; } ++cnt; }
            else seen_zero = true;
        }
        if (cnt < 1) ok = false;
    }
    if (ok) {
        for (int i = 0; i < B_ * M_; ++i) mask[i] = raw[i] ? 1 : 0;
    } else {
        const int* ri = (const int*)raw;
        for (int i = 0; i < B_ * M_; ++i) mask[i] = (ri[i] != 0) ? 1 : 0;
    }
}

// Precompute atan(w/h) per gt box (depends only on (b,m)) in fp64.
__global__ void k_pre_g(const float* __restrict__ gt_bboxes,
                        double* __restrict__ atan_g) {
    int i = blockIdx.x * blockDim.x + threadIdx.x;
    if (i >= B_ * M_) return;
    double x1 = gt_bboxes[i * 4 + 0], y1 = gt_bboxes[i * 4 + 1];
    double x2 = gt_bboxes[i * 4 + 2], y2 = gt_bboxes[i * 4 + 3];
    double w = x2 - x1, h = y2 - y1 + 1e-7;
    atan_g[i] = atan(w / h);
}

// Precompute atan(w/h) per predicted box (depends only on (b,n)) in fp64.
__global__ void k_pre_p(const float* __restrict__ pd_bboxes,
                        double* __restrict__ atan_p) {
    int i = blockIdx.x * blockDim.x + threadIdx.x;
    if (i >= B_ * N_) return;
    double x1 = pd_bboxes[(size_t)i * 4 + 0], y1 = pd_bboxes[(size_t)i * 4 + 1];
    double x2 = pd_bboxes[(size_t)i * 4 + 2], y2 = pd_bboxes[(size_t)i * 4 + 3];
    double w = x2 - x1, h = y2 - y1 + 1e-7;
    atan_p[i] = atan(w / h);
}

// ---------------------------------------------------------------------------
// K1: per (b,m,n) compute valid, overlaps (CIoU clipped), align metric (fp64).
__global__ __launch_bounds__(256) void k_metric(
    const float* __restrict__ pd_scores, const float* __restrict__ pd_bboxes,
    const float* __restrict__ anc, const int* __restrict__ gt_labels,
    const float* __restrict__ gt_bboxes, const unsigned char* __restrict__ mask,
    const double* __restrict__ atan_p, const double* __restrict__ atan_g,
    double* __restrict__ OV, double* __restrict__ AM,
    unsigned char* __restrict__ VALID) {
    int b = blockIdx.y;
    int n = blockIdx.x * 256 + threadIdx.x;

    __shared__ float s_g[M_][4];
    __shared__ int s_cls[M_];
    __shared__ unsigned char s_mask[M_];
    __shared__ double s_atg[M_];
    if (threadIdx.x < M_) {
        int gi = b * M_ + threadIdx.x;
        s_g[threadIdx.x][0] = gt_bboxes[gi * 4 + 0];
        s_g[threadIdx.x][1] = gt_bboxes[gi * 4 + 1];
        s_g[threadIdx.x][2] = gt_bboxes[gi * 4 + 2];
        s_g[threadIdx.x][3] = gt_bboxes[gi * 4 + 3];
        s_cls[threadIdx.x] = gt_labels[gi];
        s_mask[threadIdx.x] = mask[gi];
        s_atg[threadIdx.x] = atan_g[gi];
    }
    __syncthreads();
    if (n >= N_) return;

    double ax = anc[n * 2 + 0], ay = anc[n * 2 + 1];
    size_t pb = ((size_t)b * N_ + n) * 4;
    double px1 = pd_bboxes[pb + 0], py1 = pd_bboxes[pb + 1];
    double px2 = pd_bboxes[pb + 2], py2 = pd_bboxes[pb + 3];
    double atp = atan_p[(size_t)b * N_ + n];
    const float* sc = pd_scores + ((size_t)b * N_ + n) * C_;

    for (int m = 0; m < M_; ++m) {
        double gx1 = s_g[m][0], gy1 = s_g[m][1], gx2 = s_g[m][2], gy2 = s_g[m][3];
        bool inb = (ax - gx1 > 1e-9) && (ay - gy1 > 1e-9) &&
                   (gx2 - ax > 1e-9) && (gy2 - ay > 1e-9);
        bool val = inb && (s_mask[m] != 0);
        double ov = 0.0, am = 0.0;
        if (val) {
            double iw = fmin(gx2, px2) - fmax(gx1, px1); iw = iw > 0.0 ? iw : 0.0;
            double ih = fmin(gy2, py2) - fmax(gy1, py1); ih = ih > 0.0 ? ih : 0.0;
            double inter = iw * ih;
            double w1 = gx2 - gx1, h1 = gy2 - gy1 + 1e-7;
            double w2 = px2 - px1, h2 = py2 - py1 + 1e-7;
            double uni = w1 * h1 + w2 * h2 - inter + 1e-7;
            double iou = inter / uni;
            double cw = fmax(gx2, px2) - fmin(gx1, px1);
            double ch = fmax(gy2, py2) - fmin(gy1, py1);
            double c2 = cw * cw + ch * ch + 1e-7;
            double dx = px1 + px2 - gx1 - gx2, dy = py1 + py2 - gy1 - gy2;
            double rho2 = (dx * dx + dy * dy) * 0.25;
            double dv = atp - s_atg[m];
            double v = (4.0 / (M_PI * M_PI)) * dv * dv;
            double a = v / (v - iou + (1.0 + 1e-7));
            double ciou = iou - (rho2 / c2 + v * a);
            ov = ciou > 0.0 ? ciou : 0.0;
            double o2 = ov * ov;
            am = (double)sc[s_cls[m]] * (o2 * o2 * o2);
        }
        size_t idx = ((size_t)b * M_ + m) * N_ + n;
        OV[idx] = ov;
        AM[idx] = am;
        VALID[idx] = val ? 1 : 0;
    }
}

// ---------------------------------------------------------------------------
// K2: per valid (b,m) row, single-pass top-13.
// Stage A: each thread keeps a register-resident sorted top-13 (desc value,
//          ties -> lower index) of its 33 strided elements.
// Stage B: tournament merge of 256 sorted 13-lists in LDS (8 stages x 13-step
//          two-pointer merge). Total order (v desc, idx asc) == jax.lax.top_k.
__global__ __launch_bounds__(256) void k_topk(
    const double* __restrict__ AM, const unsigned char* __restrict__ VALID,
    const unsigned char* __restrict__ mask, unsigned char* __restrict__ MP) {
    int row = blockIdx.x;  // b*M + m
    if (!mask[row]) return;
    const double* r = AM + (size_t)row * N_;
    int t = threadIdx.x;

    __shared__ double sval[256 * TOPK_];
    __shared__ int    sidx[256 * TOPK_];

    // ---- Stage A: register top-13 (all indices literal -> stays in VGPRs)
    double val[TOPK_];
    int    idx[TOPK_];
#pragma unroll
    for (int j = 0; j < TOPK_; ++j) { val[j] = -1.0; idx[j] = 0x7fffffff; }

    for (int it = 0; it < 33; ++it) {
        int i = t + it * 256;
        if (i >= N_) break;
        double v = r[i];
        if (v > val[TOPK_ - 1]) {      // strictly beats current min -> insert
            double cv = v; int ci = i;
#pragma unroll
            for (int j = 0; j < TOPK_; ++j) {
                bool sw = (cv > val[j]) || (cv == val[j] && ci < idx[j]);
                double tv = val[j]; int ti = idx[j];
                if (sw) { val[j] = cv; idx[j] = ci; cv = tv; ci = ti; }
            }
        }
    }
#pragma unroll
    for (int j = 0; j < TOPK_; ++j) {
        sval[t * TOPK_ + j] = val[j];
        sidx[t * TOPK_ + j] = idx[j];
    }

    // ---- Stage B: tournament merge (lists sorted desc, ties idx-asc)
    for (int s = 128; s >= 1; s >>= 1) {
        __syncthreads();
        if (t < s) {
            int pa = t * TOPK_, pb2 = (t + s) * TOPK_;
            double ov_[TOPK_]; int oi_[TOPK_];
            int a = 0, bq = 0;
#pragma unroll
            for (int k = 0; k < TOPK_; ++k) {
                double va = sval[pa + a], vb = sval[pb2 + bq];
                int ia = sidx[pa + a], ib = sidx[pb2 + bq];
                bool takeA = (va > vb) || (va == vb && ia < ib);
                ov_[k] = takeA ? va : vb;
                oi_[k] = takeA ? ia : ib;
                if (takeA) ++a; else ++bq;
            }
#pragma unroll
            for (int k = 0; k < TOPK_; ++k) {
                sval[pa + k] = ov_[k];
                sidx[pa + k] = oi_[k];
            }
        }
    }
    __syncthreads();

    if (t < TOPK_) {
        int sel = sidx[t];
        MP[(size_t)row * N_ + sel] = VALID[(size_t)row * N_ + sel];
    }
}

// ---------------------------------------------------------------------------
// K3: per (b,n) resolve assignment; atomic-max per-gt pos_align/pos_over.
__global__ __launch_bounds__(256) void k_assign(
    const double* __restrict__ OV, const unsigned char* __restrict__ MP,
    const double* __restrict__ AM, int* __restrict__ TG,
    unsigned char* __restrict__ FG, unsigned long long* __restrict__ PAL,
    unsigned long long* __restrict__ POV) {
    int b = blockIdx.y;
    int n = blockIdx.x * 256 + threadIdx.x;
    if (n >= N_) return;

    int cnt = 0, first = -1, bestm = 0;
    double bestov = -1.0;
    for (int m = 0; m < M_; ++m) {
        size_t idx = ((size_t)b * M_ + m) * N_ + n;
        double ov = OV[idx];
        if (MP[idx]) { cnt++; if (first < 0) first = m; }
        if (ov > bestov) { bestov = ov; bestm = m; }  // strict > = first max
    }
    int tg; unsigned char fg;
    if (cnt > 1)      { tg = bestm; fg = 1; }
    else if (cnt == 1){ tg = first; fg = 1; }
    else              { tg = 0;     fg = 0; }
    TG[b * N_ + n] = tg;
    FG[b * N_ + n] = fg;
    if (fg) {
        size_t idx = ((size_t)b * M_ + tg) * N_ + n;
        // values are >= 0 so bit-pattern compare == float compare
        atomicMax(&PAL[b * M_ + tg], (unsigned long long)__double_as_longlong(AM[idx]));
        atomicMax(&POV[b * M_ + tg], (unsigned long long)__double_as_longlong(OV[idx]));
    }
}

// ---------------------------------------------------------------------------
// K4: emit outputs (concatenated float32): labels, bboxes, scores(scatter),
// fg_mask, target_gt_idx. d_out pre-zeroed by memset.
__global__ __launch_bounds__(256) void k_out(
    const int* __restrict__ TG, const unsigned char* __restrict__ FG,
    const int* __restrict__ gt_labels, const float* __restrict__ gt_bboxes,
    const double* __restrict__ AM, const unsigned long long* __restrict__ PAL,
    const unsigned long long* __restrict__ POV, float* __restrict__ out) {
    int b = blockIdx.y;
    int n = blockIdx.x * 256 + threadIdx.x;
    if (n >= N_) return;
    int i = b * N_ + n;
    int tg = TG[i];
    int fg = FG[i];
    int lab = gt_labels[b * M_ + tg];

    float* o0 = out;                            // labels  (B,N)
    float* o1 = out + (size_t)B_ * N_;          // bboxes  (B,N,4)
    float* o2 = out + (size_t)B_ * N_ * 5;      // scores  (B,N,C)
    float* o3 = out + (size_t)B_ * N_ * 85;     // fg_mask (B,N)
    float* o4 = out + (size_t)B_ * N_ * 86;     // tg_idx  (B,N)

    o0[i] = (float)lab;
    const float* gb = gt_bboxes + ((size_t)b * M_ + tg) * 4;
    o1[(size_t)i * 4 + 0] = gb[0];
    o1[(size_t)i * 4 + 1] = gb[1];
    o1[(size_t)i * 4 + 2] = gb[2];
    o1[(size_t)i * 4 + 3] = gb[3];
    o3[i] = fg ? 1.0f : 0.0f;
    o4[i] = (float)tg;
    if (fg) {
        double am = AM[((size_t)b * M_ + tg) * N_ + n];
        double pal = __longlong_as_double((long long)PAL[b * M_ + tg]);
        double pov = __longlong_as_double((long long)POV[b * M_ + tg]);
        double na = am * pov / (pal + 1e-9);
        o2[(size_t)i * C_ + lab] = (float)na;
    }
}

// ---------------------------------------------------------------------------
extern "C" void kernel_launch(void* const* d_in, const int* in_sizes, int n_in,
                              void* d_out, int out_size, void* d_ws, size_t ws_size,
                              hipStream_t stream) {
    const float* pd_scores = (const float*)d_in[0];
    const float* pd_bboxes = (const float*)d_in[1];
    const float* anc       = (const float*)d_in[2];
    const int*   gt_labels = (const int*)d_in[3];
    const float* gt_bboxes = (const float*)d_in[4];
    const unsigned char* mask_raw = (const unsigned char*)d_in[5];

    char* ws = (char*)d_ws;
    size_t off = 0;
    double* OV  = (double*)(ws + off); off += (size_t)B_ * M_ * N_ * 8;
    double* AM  = (double*)(ws + off); off += (size_t)B_ * M_ * N_ * 8;
    double* ATP = (double*)(ws + off); off += (size_t)B_ * N_ * 8;
    double* ATG = (double*)(ws + off); off += (size_t)B_ * M_ * 8;
    unsigned long long* PAL = (unsigned long long*)(ws + off); off += (size_t)B_ * M_ * 8;
    unsigned long long* POV = (unsigned long long*)(ws + off); off += (size_t)B_ * M_ * 8;
    int* TG = (int*)(ws + off); off += (size_t)B_ * N_ * 4;
    unsigned char* VALID = (unsigned char*)(ws + off); off += (size_t)B_ * M_ * N_;
    unsigned char* MP    = (unsigned char*)(ws + off); off += (size_t)B_ * M_ * N_;
    unsigned char* FG    = (unsigned char*)(ws + off); off += (size_t)B_ * N_;
    unsigned char* MASK  = (unsigned char*)(ws + off); off += (size_t)B_ * M_;

    // zero-init: outputs (scores region must be 0), mask_pos, pos_align/pos_over
    hipMemsetAsync(d_out, 0, (size_t)out_size * sizeof(float), stream);
    hipMemsetAsync(MP, 0, (size_t)B_ * M_ * N_, stream);
    hipMemsetAsync(PAL, 0, (size_t)B_ * M_ * 8 * 2, stream);  // PAL+POV adjacent

    k_decode_mask<<<1, 64, 0, stream>>>(mask_raw, MASK);
    k_pre_g<<<(B_ * M_ + 255) / 256, 256, 0, stream>>>(gt_bboxes, ATG);
    k_pre_p<<<(B_ * N_ + 255) / 256, 256, 0, stream>>>(pd_bboxes, ATP);

    dim3 gbn(NB_, B_);
    k_metric<<<gbn, 256, 0, stream>>>(pd_scores, pd_bboxes, anc, gt_labels,
                                      gt_bboxes, MASK, ATP, ATG, OV, AM, VALID);
    k_topk<<<B_ * M_, 256, 0, stream>>>(AM, VALID, MASK, MP);
    k_assign<<<gbn, 256, 0, stream>>>(OV, MP, AM, TG, FG, PAL, POV);
    k_out<<<gbn, 256, 0, stream>>>(TG, FG, gt_labels, gt_bboxes, AM, PAL, POV,
                                   (float*)d_out);
}

// Round 4
// 170.768 us; speedup vs baseline: 2.2748x; 1.2058x over previous
//
#include <hip/hip_runtime.h>
#include <math.h>

#define B_ 16
#define N_ 8400
#define M_ 32
#define C_ 80
#define TOPK_ 13

// ---------------------------------------------------------------------------
__device__ __forceinline__ bool in_gt(double ax, double ay,
    double gx1, double gy1, double gx2, double gy2) {
  return (ax - gx1 > 1e-9) && (ay - gy1 > 1e-9) &&
         (gx2 - ax > 1e-9) && (gy2 - ay > 1e-9);
}

// CIoU clipped at 0 — identical formula/order as the round-2 passing kernel.
__device__ __forceinline__ double ciou_ov(
    double px1, double py1, double px2, double py2,
    double gx1, double gy1, double gx2, double gy2,
    double atp, double atg) {
  double iw = fmin(gx2, px2) - fmax(gx1, px1); iw = iw > 0.0 ? iw : 0.0;
  double ih = fmin(gy2, py2) - fmax(gy1, py1); ih = ih > 0.0 ? ih : 0.0;
  double inter = iw * ih;
  double w1 = gx2 - gx1, h1 = gy2 - gy1 + 1e-7;
  double w2 = px2 - px1, h2 = py2 - py1 + 1e-7;
  double uni = w1 * h1 + w2 * h2 - inter + 1e-7;
  double iou = inter / uni;
  double cw = fmax(gx2, px2) - fmin(gx1, px1);
  double ch = fmax(gy2, py2) - fmin(gy1, py1);
  double c2 = cw * cw + ch * ch + 1e-7;
  double dx = px1 + px2 - gx1 - gx2, dy = py1 + py2 - gy1 - gy2;
  double rho2 = (dx * dx + dy * dy) * 0.25;
  double dv = atp - atg;
  double v = (4.0 / (M_PI * M_PI)) * dv * dv;
  double a = v / (v - iou + (1.0 + 1e-7));
  double c = iou - (rho2 / c2 + v * a);
  return c > 0.0 ? c : 0.0;
}

// ---------------------------------------------------------------------------
// P0: fused prep — atan_p (B*N), atan_g (B*M), robust mask decode (block 0).
__global__ __launch_bounds__(256) void k_prep(
    const float* __restrict__ pd_bboxes, const float* __restrict__ gt_bboxes,
    const unsigned char* __restrict__ raw,
    double* __restrict__ atp, double* __restrict__ atg,
    unsigned char* __restrict__ mask) {
  int gid = blockIdx.x * 256 + threadIdx.x;
  if (gid < B_ * N_) {
    double x1 = pd_bboxes[(size_t)gid * 4 + 0], y1 = pd_bboxes[(size_t)gid * 4 + 1];
    double x2 = pd_bboxes[(size_t)gid * 4 + 2], y2 = pd_bboxes[(size_t)gid * 4 + 3];
    atp[gid] = atan((x2 - x1) / (y2 - y1 + 1e-7));
  }
  if (gid < B_ * M_) {
    double x1 = gt_bboxes[gid * 4 + 0], y1 = gt_bboxes[gid * 4 + 1];
    double x2 = gt_bboxes[gid * 4 + 2], y2 = gt_bboxes[gid * 4 + 3];
    atg[gid] = atan((x2 - x1) / (y2 - y1 + 1e-7));
  }
  if (blockIdx.x == 0) {
    __shared__ int s_bad;
    int t = threadIdx.x;
    if (t == 0) s_bad = 0;
    __syncthreads();
    if (t < B_) {
      // validate "1-byte bool prefix mask" interpretation for row t
      int cnt = 0; bool seen0 = false; bool bad = false;
      for (int m = 0; m < M_; ++m) {
        unsigned char v = raw[t * M_ + m];
        if (v > 1) { bad = true; break; }
        if (v) { if (seen0) { bad = true; break; } ++cnt; }
        else seen0 = true;
      }
      if (cnt < 1) bad = true;
      if (bad) atomicOr(&s_bad, 1);
    }
    __syncthreads();
    bool ok = (s_bad == 0);
    const int* ri = (const int*)raw;
    for (int i = t; i < B_ * M_; i += 256)
      mask[i] = ok ? (raw[i] ? 1 : 0) : ((ri[i] != 0) ? 1 : 0);
  }
}

// ---------------------------------------------------------------------------
// K1: fused metric + top-13 per (b,m) row. Computes am fp64 on the fly,
// register-resident sorted top-13 per thread (ties -> lower index; indices
// arrive ascending so skip-on-tie is exact), then conflict-free column-major
// LDS tournament merge. Winners set bit m in MPB[b*N+n] if anchor-in-gt.
__global__ __launch_bounds__(256) void k_rowtopk(
    const float* __restrict__ pd_scores, const float* __restrict__ pd_bboxes,
    const float* __restrict__ anc, const int* __restrict__ gt_labels,
    const float* __restrict__ gt_bboxes, const unsigned char* __restrict__ mask,
    const double* __restrict__ atp, const double* __restrict__ atg,
    unsigned int* __restrict__ MPB) {
  int row = blockIdx.x;            // b*M + m
  if (!mask[row]) return;
  int b = row >> 5, m = row & 31;
  int t = threadIdx.x;

  double gx1 = gt_bboxes[row * 4 + 0], gy1 = gt_bboxes[row * 4 + 1];
  double gx2 = gt_bboxes[row * 4 + 2], gy2 = gt_bboxes[row * 4 + 3];
  double atgm = atg[row];
  int cls = gt_labels[row];

  const float4* pb4 = (const float4*)(pd_bboxes + (size_t)b * N_ * 4);
  const float2* an2 = (const float2*)anc;
  const double* ap  = atp + (size_t)b * N_;
  const float*  scp = pd_scores + (size_t)b * N_ * C_ + cls;

  double tv[TOPK_]; int ti[TOPK_];
#pragma unroll
  for (int j = 0; j < TOPK_; ++j) { tv[j] = -1.0; ti[j] = 0x7fffffff; }

  auto body = [&](int n) {
    float4 pbox = pb4[n];
    double atpn = ap[n];
    float  svc  = scp[(size_t)n * C_];
    float2 a2   = an2[n];
    bool val = in_gt((double)a2.x, (double)a2.y, gx1, gy1, gx2, gy2);
    double am = 0.0;
    if (val) {
      double ov = ciou_ov((double)pbox.x, (double)pbox.y, (double)pbox.z,
                          (double)pbox.w, gx1, gy1, gx2, gy2, atpn, atgm);
      double o2 = ov * ov;
      am = (double)svc * (o2 * o2 * o2);
    }
    if (am > tv[TOPK_ - 1]) {
      double cv = am; int ci = n;
#pragma unroll
      for (int j = 0; j < TOPK_; ++j) {
        bool sw = (cv > tv[j]) || (cv == tv[j] && ci < ti[j]);
        double xv = tv[j]; int xi = ti[j];
        if (sw) { tv[j] = cv; ti[j] = ci; cv = xv; ci = xi; }
      }
    }
  };

  for (int it = 0; it < 32; ++it) body(t + it * 256);   // 32*256 = 8192
  if (t < N_ - 8192) body(t + 8192);                    // tail 208

  // column-major LDS lists: element j of list t at [j*256 + t] (conflict-free)
  __shared__ double sval[TOPK_ * 256];
  __shared__ int    sidx[TOPK_ * 256];
#pragma unroll
  for (int j = 0; j < TOPK_; ++j) { sval[j * 256 + t] = tv[j]; sidx[j * 256 + t] = ti[j]; }

  for (int s = 128; s >= 1; s >>= 1) {
    __syncthreads();
    if (t < s) {
      double ov_[TOPK_]; int oi_[TOPK_];
      int a = 0, bq = 0;
#pragma unroll
      for (int k = 0; k < TOPK_; ++k) {
        double va = sval[a * 256 + t],  vb = sval[bq * 256 + t + s];
        int    ia = sidx[a * 256 + t],  ib = sidx[bq * 256 + t + s];
        bool takeA = (va > vb) || (va == vb && ia < ib);
        ov_[k] = takeA ? va : vb;
        oi_[k] = takeA ? ia : ib;
        if (takeA) ++a; else ++bq;
      }
#pragma unroll
      for (int k = 0; k < TOPK_; ++k) { sval[k * 256 + t] = ov_[k]; sidx[k * 256 + t] = oi_[k]; }
    }
  }
  __syncthreads();

  if (t < TOPK_) {
    int n = sidx[t * 256];           // element t of merged list 0
    float2 a2 = an2[n];
    if (in_gt((double)a2.x, (double)a2.y, gx1, gy1, gx2, gy2))  // mask_topk & valid
      atomicOr(&MPB[(size_t)b * N_ + n], 1u << m);
  }
}

// ---------------------------------------------------------------------------
// K2: per (b,n) resolve assignment from MPB bitmask; recompute overlaps
// in-register for the rare multi-assignment columns; atomicMax PAL/POV.
__global__ __launch_bounds__(256) void k_colassign(
    const float* __restrict__ pd_scores, const float* __restrict__ pd_bboxes,
    const float* __restrict__ anc, const int* __restrict__ gt_labels,
    const float* __restrict__ gt_bboxes, const unsigned char* __restrict__ mask,
    const double* __restrict__ atp, const double* __restrict__ atg,
    const unsigned int* __restrict__ MPB,
    unsigned char* __restrict__ TG, unsigned char* __restrict__ FG,
    unsigned long long* __restrict__ PAL, unsigned long long* __restrict__ POV) {
  int b = blockIdx.y;
  int n = blockIdx.x * 256 + threadIdx.x;

  __shared__ float s_g[M_][4];
  __shared__ double s_atg[M_];
  __shared__ int s_cls[M_];
  __shared__ unsigned char s_msk[M_];
  if (threadIdx.x < M_) {
    int gi = b * M_ + threadIdx.x;
    s_g[threadIdx.x][0] = gt_bboxes[gi * 4 + 0];
    s_g[threadIdx.x][1] = gt_bboxes[gi * 4 + 1];
    s_g[threadIdx.x][2] = gt_bboxes[gi * 4 + 2];
    s_g[threadIdx.x][3] = gt_bboxes[gi * 4 + 3];
    s_atg[threadIdx.x] = atg[gi];
    s_cls[threadIdx.x] = gt_labels[gi];
    s_msk[threadIdx.x] = mask[gi];
  }
  __syncthreads();
  if (n >= N_) return;

  unsigned int mpb = MPB[(size_t)b * N_ + n];
  int cnt = __popc(mpb);
  int tg = 0; unsigned char fg = 0;

  if (cnt == 1) { tg = __ffs(mpb) - 1; fg = 1; }
  else if (cnt > 1) {
    // argmax over all 32 m of masked/clipped overlaps (first-max on ties)
    float2 a2 = ((const float2*)anc)[n];
    float4 pbox = ((const float4*)(pd_bboxes + (size_t)b * N_ * 4))[n];
    double atpn = atp[(size_t)b * N_ + n];
    double best = -1.0;
    for (int mm = 0; mm < M_; ++mm) {
      double g0 = s_g[mm][0], g1 = s_g[mm][1], g2 = s_g[mm][2], g3 = s_g[mm][3];
      bool val = s_msk[mm] && in_gt((double)a2.x, (double)a2.y, g0, g1, g2, g3);
      double ov = val ? ciou_ov((double)pbox.x, (double)pbox.y, (double)pbox.z,
                                (double)pbox.w, g0, g1, g2, g3, atpn, s_atg[mm])
                      : 0.0;
      if (ov > best) { best = ov; tg = mm; }
    }
    fg = 1;
  }

  TG[(size_t)b * N_ + n] = (unsigned char)tg;
  FG[(size_t)b * N_ + n] = fg;

  if (fg) {
    float2 a2 = ((const float2*)anc)[n];
    float4 pbox = ((const float4*)(pd_bboxes + (size_t)b * N_ * 4))[n];
    double atpn = atp[(size_t)b * N_ + n];
    double g0 = s_g[tg][0], g1 = s_g[tg][1], g2 = s_g[tg][2], g3 = s_g[tg][3];
    bool val = s_msk[tg] && in_gt((double)a2.x, (double)a2.y, g0, g1, g2, g3);
    double ov = val ? ciou_ov((double)pbox.x, (double)pbox.y, (double)pbox.z,
                              (double)pbox.w, g0, g1, g2, g3, atpn, s_atg[tg])
                    : 0.0;
    double o2 = ov * ov;
    double am = (double)pd_scores[((size_t)b * N_ + n) * C_ + s_cls[tg]] * (o2 * o2 * o2);
    atomicMax(&PAL[b * M_ + tg], (unsigned long long)__double_as_longlong(am));
    atomicMax(&POV[b * M_ + tg], (unsigned long long)__double_as_longlong(ov));
  }
}

// ---------------------------------------------------------------------------
// K3: emit ALL outputs (no memset needed): 64 anchors per block.
__global__ __launch_bounds__(256) void k_emit(
    const float* __restrict__ pd_scores, const float* __restrict__ pd_bboxes,
    const float* __restrict__ anc, const int* __restrict__ gt_labels,
    const float* __restrict__ gt_bboxes, const unsigned char* __restrict__ mask,
    const double* __restrict__ atp, const double* __restrict__ atg,
    const unsigned char* __restrict__ TG, const unsigned char* __restrict__ FG,
    const unsigned long long* __restrict__ PAL,
    const unsigned long long* __restrict__ POV,
    float* __restrict__ out) {
  int b = blockIdx.y;
  int n0 = blockIdx.x * 64;
  int t = threadIdx.x;

  __shared__ float s_g[M_][4];
  __shared__ double s_atg[M_];
  __shared__ int s_cls[M_];
  __shared__ unsigned char s_msk[M_];
  __shared__ float s_na[64];
  __shared__ int   s_lab[64];
  __shared__ int   s_tg[64];
  __shared__ unsigned char s_fg[64];
  if (t < M_) {
    int gi = b * M_ + t;
    s_g[t][0] = gt_bboxes[gi * 4 + 0];
    s_g[t][1] = gt_bboxes[gi * 4 + 1];
    s_g[t][2] = gt_bboxes[gi * 4 + 2];
    s_g[t][3] = gt_bboxes[gi * 4 + 3];
    s_atg[t] = atg[gi];
    s_cls[t] = gt_labels[gi];
    s_msk[t] = mask[gi];
  }
  __syncthreads();

  if (t < 64) {
    int n = n0 + t;
    if (n < N_) {
      int tg = TG[(size_t)b * N_ + n];
      unsigned char fg = FG[(size_t)b * N_ + n];
      float na = 0.0f;
      if (fg) {
        float2 a2 = ((const float2*)anc)[n];
        float4 pbox = ((const float4*)(pd_bboxes + (size_t)b * N_ * 4))[n];
        double atpn = atp[(size_t)b * N_ + n];
        double g0 = s_g[tg][0], g1 = s_g[tg][1], g2 = s_g[tg][2], g3 = s_g[tg][3];
        bool val = s_msk[tg] && in_gt((double)a2.x, (double)a2.y, g0, g1, g2, g3);
        double ov = val ? ciou_ov((double)pbox.x, (double)pbox.y, (double)pbox.z,
                                  (double)pbox.w, g0, g1, g2, g3, atpn, s_atg[tg])
                        : 0.0;
        double o2 = ov * ov;
        double am = (double)pd_scores[((size_t)b * N_ + n) * C_ + s_cls[tg]] * (o2 * o2 * o2);
        double pal = __longlong_as_double((long long)PAL[b * M_ + tg]);
        double pov = __longlong_as_double((long long)POV[b * M_ + tg]);
        na = (float)(am * pov / (pal + 1e-9));
      }
      s_na[t] = na; s_lab[t] = s_cls[tg]; s_tg[t] = tg; s_fg[t] = fg;
    }
  }
  __syncthreads();

  float* o0 = out;                         // labels  (B,N)
  float* o1 = out + (size_t)B_ * N_;       // bboxes  (B,N,4)
  float* o2 = out + (size_t)B_ * N_ * 5;   // scores  (B,N,C)
  float* o3 = out + (size_t)B_ * N_ * 85;  // fg_mask (B,N)
  float* o4 = out + (size_t)B_ * N_ * 86;  // tg_idx  (B,N)

  if (t < 64) {
    int n = n0 + t;
    if (n < N_) {
      size_t i = (size_t)b * N_ + n;
      o0[i] = (float)s_lab[t];
      o3[i] = s_fg[t] ? 1.0f : 0.0f;
      o4[i] = (float)s_tg[t];
      int tg = s_tg[t];
      float4 gb = make_float4(s_g[tg][0], s_g[tg][1], s_g[tg][2], s_g[tg][3]);
      ((float4*)o1)[i] = gb;
    }
  }

  // score rows: 64 anchors x 20 float4 = 1280 float4s; 5 per thread
#pragma unroll
  for (int k = 0; k < 5; ++k) {
    int id = t + k * 256;
    int a = id / 20, j = id % 20;
    int n = n0 + a;
    if (n < N_) {
      int lab = s_lab[a];
      float na = s_fg[a] ? s_na[a] : 0.0f;
      int c0 = 4 * j;
      float4 w;
      w.x = (c0 + 0 == lab) ? na : 0.0f;
      w.y = (c0 + 1 == lab) ? na : 0.0f;
      w.z = (c0 + 2 == lab) ? na : 0.0f;
      w.w = (c0 + 3 == lab) ? na : 0.0f;
      ((float4*)(o2 + ((size_t)b * N_ + n) * C_))[j] = w;
    }
  }
}

// ---------------------------------------------------------------------------
extern "C" void kernel_launch(void* const* d_in, const int* in_sizes, int n_in,
                              void* d_out, int out_size, void* d_ws, size_t ws_size,
                              hipStream_t stream) {
  const float* pd_scores = (const float*)d_in[0];
  const float* pd_bboxes = (const float*)d_in[1];
  const float* anc       = (const float*)d_in[2];
  const int*   gt_labels = (const int*)d_in[3];
  const float* gt_bboxes = (const float*)d_in[4];
  const unsigned char* mask_raw = (const unsigned char*)d_in[5];

  char* ws = (char*)d_ws;
  size_t off = 0;
  double* ATP = (double*)(ws + off); off += (size_t)B_ * N_ * 8;
  double* ATG = (double*)(ws + off); off += (size_t)B_ * M_ * 8;
  unsigned int* MPB = (unsigned int*)(ws + off); size_t mpb_off = off; off += (size_t)B_ * N_ * 4;
  unsigned long long* PAL = (unsigned long long*)(ws + off); off += (size_t)B_ * M_ * 8;
  unsigned long long* POV = (unsigned long long*)(ws + off); off += (size_t)B_ * M_ * 8;
  unsigned char* TG   = (unsigned char*)(ws + off); off += (size_t)B_ * N_;
  unsigned char* FG   = (unsigned char*)(ws + off); off += (size_t)B_ * N_;
  unsigned char* MASK = (unsigned char*)(ws + off); off += (size_t)B_ * M_;

  // single memset covers MPB + PAL + POV (contiguous)
  hipMemsetAsync(ws + mpb_off, 0, (size_t)B_ * N_ * 4 + (size_t)B_ * M_ * 16, stream);

  k_prep<<<(B_ * N_ + 255) / 256, 256, 0, stream>>>(pd_bboxes, gt_bboxes,
                                                    mask_raw, ATP, ATG, MASK);
  k_rowtopk<<<B_ * M_, 256, 0, stream>>>(pd_scores, pd_bboxes, anc, gt_labels,
                                         gt_bboxes, MASK, ATP, ATG, MPB);
  dim3 gbn((N_ + 255) / 256, B_);
  k_colassign<<<gbn, 256, 0, stream>>>(pd_scores, pd_bboxes, anc, gt_labels,
                                       gt_bboxes, MASK, ATP, ATG, MPB,
                                       TG, FG, PAL, POV);
  dim3 gem((N_ + 63) / 64, B_);
  k_emit<<<gem, 256, 0, stream>>>(pd_scores, pd_bboxes, anc, gt_labels,
                                  gt_bboxes, MASK, ATP, ATG, TG, FG, PAL, POV,
                                  (float*)d_out);
}